// Round 8
// baseline (275.514 us; speedup 1.0000x reference)
//
#include <hip/hip_runtime.h>
#include <math.h>

#define SEQ    2048
#define DMODEL 1024
#define NH     16
#define DH     64
#define NB     2
#define BHN    (NB*NH)

static constexpr float SCALE  = 0.02209708691207961f;                    // 1/sqrt(2048)
static constexpr float SCALE2 = 0.02209708691207961f * 1.4426950408889634f; // *log2(e), for exp2

typedef __attribute__((ext_vector_type(8))) short short8;
typedef __attribute__((ext_vector_type(4))) short short4v;
typedef __attribute__((ext_vector_type(4))) float f32x4;

__device__ __forceinline__ short f2bf(float f) {
    union { float f; unsigned u; } v; v.f = f;
    unsigned r = (v.u + 0x7FFFu + ((v.u >> 16) & 1u)) >> 16;
    return (short)r;
}

// pack two floats to bf16x2 (round-half-up): low16 = a, high16 = b
__device__ __forceinline__ unsigned pack_bf2(float a, float b) {
    union { float f; unsigned u; } ua, ub; ua.f = a; ub.f = b;
    return __builtin_amdgcn_perm(ub.u + 0x8000u, ua.u + 0x8000u, 0x07060302u);
}

__device__ __forceinline__ float bf2f(short s) {
    union { unsigned u; float f; } v; v.u = ((unsigned)(unsigned short)s) << 16;
    return v.f;
}

__device__ __forceinline__ void load16_lds(const short* g, short* l) {
    __builtin_amdgcn_global_load_lds(
        (const __attribute__((address_space(1))) unsigned int*)g,
        (__attribute__((address_space(3))) unsigned int*)l,
        16, 0, 0);
}

// Stage nIter*32 rows of a [rows][64] bf16 tile (row stride ldg) into LDS with
// XOR-8-block swizzle: LDS[row][b] = G[row][b ^ (row&7)] (blocks of 8 elements).
__device__ __forceinline__ void stage_rows(const short* g, short* s, int t, int ldg, int nIter) {
    int wave = t >> 6, lane = t & 63;
    #pragma unroll
    for (int i = 0; i < 4; ++i) {
        if (i >= nIter) break;
        int E   = i * 2048 + wave * 512 + lane * 8;
        int row = E >> 6;
        int blk = (lane & 7) ^ (row & 7);
        load16_lds(g + (size_t)row * ldg + blk * 8, s + i * 2048 + wave * 512);
    }
}

// Read an MFMA A/B fragment from a swizzled [rows][64] LDS tile.
// lane: m/n = rowbase + (lane&15), k = (lane>>4)*8 + j + ks*32
__device__ __forceinline__ short8 frag_sw(const short* s, int rowbase, int ks, int lane) {
    int m   = rowbase + (lane & 15);
    int q   = lane >> 4;
    int blk = (ks * 4 + q) ^ (m & 7);
    return *(const short8*)(s + m * 64 + blk * 8);
}

// Complementary work-tile swizzle: blocks aliasing onto the same CU (same x)
// get tile indices summing to a constant. Bijective (x,y) -> (tile, bh).
__device__ __forceinline__ void swizzle_tile(int x, int y, int& tile, int& bh) {
    int r = y >> 3;
    bh = (y & 7) * 4 + r;
    int xs = (r & 2) ? ((x + 16) & 31) : x;
    tile = (r & 1) ? (31 - xs) : xs;
}

// ---------------- converters ----------------
__global__ __launch_bounds__(256) void convert_x(
    const float* __restrict__ q, const float* __restrict__ k, const float* __restrict__ v,
    short* __restrict__ Xq, short* __restrict__ Xk, short* __restrict__ Xv)
{
    const int z = blockIdx.z;
    const float* src = (z == 0) ? q : (z == 1) ? k : v;
    short* dst = (z == 0) ? Xq : (z == 1) ? Xk : Xv;
    size_t idx = ((size_t)blockIdx.x * 256 + threadIdx.x) * 8;
    float4 a = *(const float4*)(src + idx);
    float4 b = *(const float4*)(src + idx + 4);
    short8 o;
    o[0] = f2bf(a.x); o[1] = f2bf(a.y); o[2] = f2bf(a.z); o[3] = f2bf(a.w);
    o[4] = f2bf(b.x); o[5] = f2bf(b.y); o[6] = f2bf(b.z); o[7] = f2bf(b.w);
    *(short8*)(dst + idx) = o;
}

// W[h][k][e] (z<3) or WO[k][n] (z==3)  ->  Wt[n][k] bf16 (n = h*64+e)
__global__ __launch_bounds__(256) void convert_w(
    const float* __restrict__ WQ, const float* __restrict__ WK,
    const float* __restrict__ WV, const float* __restrict__ WO,
    short* __restrict__ WQt, short* __restrict__ WKt,
    short* __restrict__ WVt, short* __restrict__ WOt)
{
    const int z = blockIdx.z;
    const int k0 = blockIdx.x * 64;
    const int ny = blockIdx.y;            // n-tile = head for z<3
    const float* W = (z == 0) ? WQ : (z == 1) ? WK : (z == 2) ? WV : WO;
    short* Wt = (z == 0) ? WQt : (z == 1) ? WKt : (z == 2) ? WVt : WOt;

    __shared__ float Ts[64][68];          // [n-local][k-local]
    const int t = threadIdx.x;
    const int tr = t >> 4, tc4 = (t & 15) * 4;

    #pragma unroll
    for (int i = 0; i < 4; ++i) {
        int row = tr + i * 16;            // k-local
        float4 v;
        if (z < 3) v = *(const float4*)(W + (size_t)ny * DMODEL * DH + (size_t)(k0 + row) * DH + tc4);
        else       v = *(const float4*)(W + (size_t)(k0 + row) * DMODEL + ny * 64 + tc4);
        Ts[tc4 + 0][row] = v.x; Ts[tc4 + 1][row] = v.y;
        Ts[tc4 + 2][row] = v.z; Ts[tc4 + 3][row] = v.w;
    }
    __syncthreads();
    #pragma unroll
    for (int i = 0; i < 4; ++i) {
        int nl = tr + i * 16;
        short4v o;
        o[0] = f2bf(Ts[nl][tc4 + 0]); o[1] = f2bf(Ts[nl][tc4 + 1]);
        o[2] = f2bf(Ts[nl][tc4 + 2]); o[3] = f2bf(Ts[nl][tc4 + 3]);
        *(short4v*)(Wt + (size_t)(ny * 64 + nl) * DMODEL + k0 + tc4) = o;
    }
}

// ---------------- NT-GEMM: C = X[m][k] * Wt[n][k]^T ----------------
__global__ __launch_bounds__(256) void gemm_nt(
    const short* __restrict__ A0, const short* __restrict__ A1, const short* __restrict__ A2,
    const short* __restrict__ B0, const short* __restrict__ B1, const short* __restrict__ B2,
    short* __restrict__ Y0, short* __restrict__ Y1, short* __restrict__ Y2,
    float* __restrict__ outF, int phase)
{
    const int z = blockIdx.z;
    const short* X  = (phase == 1) ? A0 : (z == 0) ? A0 : (z == 1) ? A1 : A2;
    const short* Wt = (phase == 1) ? B0 : (z == 0) ? B0 : (z == 1) ? B1 : B2;
    short* Y        = (z == 0) ? Y0 : (z == 1) ? Y1 : Y2;
    const bool vOrient = (phase == 0) && (z == 2);

    const int n0 = blockIdx.x * 128;
    const int m0 = blockIdx.y * 128;

    __shared__ short As[128 * 64];
    __shared__ short Bs[128 * 64];

    const int t = threadIdx.x;
    const int wave = t >> 6, lane = t & 63;
    const int wrow = (wave >> 1) * 64, wcol = (wave & 1) * 64;
    const int quad = lane >> 4, l15 = lane & 15;

    f32x4 acc[4][4];
    #pragma unroll
    for (int i = 0; i < 4; ++i)
        #pragma unroll
        for (int j = 0; j < 4; ++j)
            acc[i][j] = (f32x4)0.f;

    for (int k0 = 0; k0 < DMODEL; k0 += 64) {
        __syncthreads();
        stage_rows(X  + (size_t)m0 * DMODEL + k0, As, t, DMODEL, 4);
        stage_rows(Wt + (size_t)n0 * DMODEL + k0, Bs, t, DMODEL, 4);
        __syncthreads();
        if (!vOrient) {
            #pragma unroll
            for (int ks = 0; ks < 2; ++ks) {
                short8 xf[4], wf[4];
                #pragma unroll
                for (int i = 0; i < 4; ++i) xf[i] = frag_sw(As, wrow + i * 16, ks, lane);
                #pragma unroll
                for (int i = 0; i < 4; ++i) wf[i] = frag_sw(Bs, wcol + i * 16, ks, lane);
                #pragma unroll
                for (int a = 0; a < 4; ++a)
                    #pragma unroll
                    for (int b = 0; b < 4; ++b)
                        acc[a][b] = __builtin_amdgcn_mfma_f32_16x16x32_bf16(
                            wf[a], xf[b], acc[a][b], 0, 0, 0);
            }
        } else {
            #pragma unroll
            for (int ks = 0; ks < 2; ++ks) {
                short8 xf[4], wf[4];
                #pragma unroll
                for (int i = 0; i < 4; ++i) xf[i] = frag_sw(As, wrow + i * 16, ks, lane);
                #pragma unroll
                for (int i = 0; i < 4; ++i) wf[i] = frag_sw(Bs, wcol + i * 16, ks, lane);
                #pragma unroll
                for (int a = 0; a < 4; ++a)
                    #pragma unroll
                    for (int b = 0; b < 4; ++b)
                        acc[a][b] = __builtin_amdgcn_mfma_f32_16x16x32_bf16(
                            xf[a], wf[b], acc[a][b], 0, 0, 0);
            }
        }
    }

    if (vOrient) {
        // D[m][n]: rows m = s (4 consecutive), col n = (h,e) -> Vt[bh][e][s]
        #pragma unroll
        for (int a = 0; a < 4; ++a) {
            #pragma unroll
            for (int b = 0; b < 4; ++b) {
                int m = m0 + wrow + a * 16 + quad * 4;
                int n = n0 + wcol + b * 16 + l15;
                int bb = m >> 11, s = m & 2047, h = n >> 6, e = n & 63;
                short4v o;
                #pragma unroll
                for (int i = 0; i < 4; ++i) o[i] = f2bf(acc[a][b][i]);
                *(short4v*)(Y + ((size_t)((bb * NH + h) * DH + e)) * SEQ + s) = o;
            }
        }
    } else if (phase == 1) {
        #pragma unroll
        for (int a = 0; a < 4; ++a) {
            #pragma unroll
            for (int b = 0; b < 4; ++b) {
                int n = n0 + wcol + a * 16 + quad * 4;
                int m = m0 + wrow + b * 16 + l15;
                float4 o = make_float4(acc[a][b][0], acc[a][b][1], acc[a][b][2], acc[a][b][3]);
                *(float4*)(outF + (size_t)m * DMODEL + n) = o;
            }
        }
    } else {
        #pragma unroll
        for (int a = 0; a < 4; ++a) {
            #pragma unroll
            for (int b = 0; b < 4; ++b) {
                int n = n0 + wcol + a * 16 + quad * 4;
                int m = m0 + wrow + b * 16 + l15;
                int bb = m >> 11, s = m & 2047, h = n >> 6, e = n & 63;
                short4v o;
                #pragma unroll
                for (int i = 0; i < 4; ++i) o[i] = f2bf(acc[a][b][i]);
                *(short4v*)(Y + ((size_t)((bb * NH + h) * SEQ + s)) * DH + e) = o;
            }
        }
    }
}

// ---------------- stats tile: dsum[i] += sum over 64 q of exp2(...) ----------------
// MODE 0: full tile (k <= q guaranteed).  MODE 1: diagonal (EXACT integer mask).
// MODE 2: no-mask general (bias applied only where bias<0, all terms counted).
template<int MODE>
__device__ __forceinline__ void stats_tile_w(
    const short* Qbuf, const short8 Kf[2], const float bias[4][4],
    float dsum[4], int lane, int wave16)
{
    const int quad = lane >> 4, l15 = lane & 15;
    f32x4 acc[4];
    #pragma unroll
    for (int nt = 0; nt < 4; ++nt) acc[nt] = (f32x4)0.f;
    #pragma unroll
    for (int ks = 0; ks < 2; ++ks) {
        #pragma unroll
        for (int nt = 0; nt < 4; ++nt)
            acc[nt] = __builtin_amdgcn_mfma_f32_16x16x32_bf16(
                Kf[ks], frag_sw(Qbuf, nt * 16, ks, lane), acc[nt], 0, 0, 0);
    }
    #pragma unroll
    for (int nt = 0; nt < 4; ++nt) {
        #pragma unroll
        for (int i = 0; i < 4; ++i) {
            float bi = bias[nt][i];
            float v = (MODE == 2) ? fmaf(acc[nt][i], SCALE2, fminf(bi, 0.f))
                                  : fmaf(acc[nt][i], SCALE2, bi);
            float e = exp2f(v);
            if (MODE == 1)
                e = ((wave16 + quad * 4 + i) <= (nt * 16 + l15)) ? e : 0.f;
            dsum[i] += e;
        }
    }
}

// grid (32,32) swizzled. Computes rD for its k-tile, then scales Vt in place
// (Vt[bh][e][k0..k0+63] *= rD) — the former scale_vt kernel, fused.
__global__ __launch_bounds__(256) void stats_mfma(
    const short* __restrict__ Qg, const short* __restrict__ Kg,
    short* __restrict__ Vt, const int* __restrict__ mask_p)
{
    int kt, bh;
    swizzle_tile(blockIdx.x, blockIdx.y, kt, bh);
    const int k0 = kt * 64;
    const int masking = mask_p[0];

    __shared__ short Ks[64 * 64];
    __shared__ short Qs[2][64 * 64];
    __shared__ float rDs[64];

    const int t = threadIdx.x;
    const int wave = t >> 6, lane = t & 63;
    const int quad = lane >> 4, l15 = lane & 15;

    const int q0s = masking ? k0 : 0;
    stage_rows(Kg + ((size_t)bh * SEQ + k0) * DH, Ks, t, DH, 2);
    stage_rows(Qg + ((size_t)bh * SEQ + q0s) * DH, Qs[0], t, DH, 2);
    __syncthreads();

    short8 Kf[2];
    Kf[0] = frag_sw(Ks, wave * 16, 0, lane);
    Kf[1] = frag_sw(Ks, wave * 16, 1, lane);

    float bias[4][4];
    #pragma unroll
    for (int nt = 0; nt < 4; ++nt)
        #pragma unroll
        for (int i = 0; i < 4; ++i)
            bias[nt][i] = SCALE2 * (float)((k0 + wave * 16 + quad * 4 + i)
                                         - (q0s + nt * 16 + l15));

    float dsum[4] = {0.f, 0.f, 0.f, 0.f};
    const int nIter = (SEQ - q0s) / 64;
    for (int it = 0; it < nIter; ++it) {
        const int cur = it & 1;
        if (it > 0) __syncthreads();
        if (it + 1 < nIter)
            stage_rows(Qg + ((size_t)bh * SEQ + q0s + (it + 1) * 64) * DH, Qs[1 - cur], t, DH, 2);
        if (!masking)      stats_tile_w<2>(Qs[cur], Kf, bias, dsum, lane, wave * 16);
        else if (it == 0)  stats_tile_w<1>(Qs[cur], Kf, bias, dsum, lane, wave * 16);
        else               stats_tile_w<0>(Qs[cur], Kf, bias, dsum, lane, wave * 16);
        #pragma unroll
        for (int nt = 0; nt < 4; ++nt)
            #pragma unroll
            for (int i = 0; i < 4; ++i)
                bias[nt][i] -= 64.f * SCALE2;
    }

    #pragma unroll
    for (int i = 0; i < 4; ++i) {
        float d = dsum[i];
        #pragma unroll
        for (int mm = 1; mm < 16; mm <<= 1) d += __shfl_xor(d, mm);
        dsum[i] = d;
    }
    if (l15 == 0) {
        const int kloc = wave * 16 + quad * 4;
        float4 o = make_float4(1.f / dsum[0], 1.f / dsum[1], 1.f / dsum[2], 1.f / dsum[3]);
        *(float4*)&rDs[kloc] = o;
    }
    __syncthreads();

    // scale Vt[bh][e][k0 + 0..63] by rDs (this block exclusively owns the slice)
    short* vp = Vt + (size_t)bh * DH * SEQ + k0;
    #pragma unroll
    for (int c = t; c < 512; c += 256) {
        int e = c >> 3, sc = (c & 7) * 8;
        short* p = vp + (size_t)e * SEQ + sc;
        short8 v = *(short8*)p;
        union { unsigned u[4]; short8 s8; } o;
        #pragma unroll
        for (int j = 0; j < 4; ++j)
            o.u[j] = pack_bf2(bf2f(v[2 * j]) * rDs[sc + 2 * j],
                              bf2f(v[2 * j + 1]) * rDs[sc + 2 * j + 1]);
        *(short8*)p = o.s8;
    }
}

// ---------------- attn tile: scores S^T, wave-private P, PV ----------------
// MODE 1 uses an EXACT integer causal test (kloc <= qloc).
template<int MODE>
__device__ __forceinline__ void attn_tile(
    const short* Kbuf, const short* Vbuf, short* Pw,
    const short8 Qf[2], const float bias[4][4], f32x4 oacc[4],
    int lane, int quad, int l15, int qloc)
{
    // scores: D[k][q], per-lane k = mt*16 + quad*4 + i, q = this wave's l15
    f32x4 sacc[4];
    #pragma unroll
    for (int mt = 0; mt < 4; ++mt) sacc[mt] = (f32x4)0.f;
    #pragma unroll
    for (int ks = 0; ks < 2; ++ks) {
        #pragma unroll
        for (int mt = 0; mt < 4; ++mt)
            sacc[mt] = __builtin_amdgcn_mfma_f32_16x16x32_bf16(
                frag_sw(Kbuf, mt * 16, ks, lane), Qf[ks], sacc[mt], 0, 0, 0);
    }
    // compiler memory fence: prior LDS reads must not sink below the P overwrite
    __asm__ volatile("" ::: "memory");
    // P = exp2(s*SCALE2 + bias2), wave-private swizzled store (4 consecutive k)
    #pragma unroll
    for (int mt = 0; mt < 4; ++mt) {
        float p[4];
        #pragma unroll
        for (int i = 0; i < 4; ++i) {
            float bi = bias[mt][i];
            float v = (MODE == 2) ? fmaf(sacc[mt][i], SCALE2, fminf(bi, 0.f))
                                  : fmaf(sacc[mt][i], SCALE2, bi);
            float e = exp2f(v);
            if (MODE == 1)
                e = ((mt * 16 + quad * 4 + i) <= qloc) ? e : 0.f;
            p[i] = e;
        }
        int blk = (2 * mt + (quad >> 1)) ^ (l15 & 7);
        *(uint2*)(Pw + l15 * 64 + blk * 8 + (quad & 1) * 4) =
            make_uint2(pack_bf2(p[0], p[1]), pack_bf2(p[2], p[3]));
    }
    // fence: PV fragment reads must not hoist above the P writes.
    __asm__ volatile("" ::: "memory");
    // PV: O^T[e][q] += Vt[e][k] * P[q][k]; B-frag read back from wave-private P
    #pragma unroll
    for (int ks = 0; ks < 2; ++ks) {
        short8 pf = *(const short8*)(Pw + l15 * 64 + (((ks * 4 + quad) ^ (l15 & 7)) * 8));
        #pragma unroll
        for (int mt = 0; mt < 4; ++mt)
            oacc[mt] = __builtin_amdgcn_mfma_f32_16x16x32_bf16(
                frag_sw(Vbuf, mt * 16, ks, lane), pf, oacc[mt], 0, 0, 0);
    }
}

// grid (32,32) swizzled. V pre-scaled by rD. Single-buffered K/V: LDS = 24 KiB
// -> 6 blocks/CU (was 40 KiB / 4 blocks): stall-filling via block overlap.
__global__ __launch_bounds__(256) void attn_mfma(
    const short* __restrict__ Qg, const short* __restrict__ Kg, const short* __restrict__ Vt,
    short* __restrict__ attnb, const int* __restrict__ mask_p)
{
    int qt, bh;
    swizzle_tile(blockIdx.x, blockIdx.y, qt, bh);
    const int b = bh / NH, h = bh % NH;
    const int q0 = qt * 64;
    const int masking = mask_p[0];

    __shared__ short Qs[64 * 64];        // becomes wave-private P after preload
    __shared__ short Ks[64 * 64];
    __shared__ short Vts[64 * 64];

    const int t = threadIdx.x;
    const int wave = t >> 6, lane = t & 63;
    const int quad = lane >> 4, l15 = lane & 15;
    short* Pw = Qs + wave * 1024;
    const int qloc = wave * 16 + l15;    // q index local to this 64-tile

    stage_rows(Qg + ((size_t)bh * SEQ + q0) * DH, Qs, t, DH, 2);
    __syncthreads();

    short8 Qf[2];
    Qf[0] = frag_sw(Qs, wave * 16, 0, lane);
    Qf[1] = frag_sw(Qs, wave * 16, 1, lane);

    float bias[4][4];
    #pragma unroll
    for (int mt = 0; mt < 4; ++mt)
        #pragma unroll
        for (int i = 0; i < 4; ++i)
            bias[mt][i] = SCALE2 * (float)((mt * 16 + quad * 4 + i)
                                         - (q0 + qloc));

    f32x4 oacc[4];
    #pragma unroll
    for (int mt = 0; mt < 4; ++mt) oacc[mt] = (f32x4)0.f;

    const int nIter = masking ? (qt + 1) : (SEQ / 64);
    for (int it = 0; it < nIter; ++it) {
        __syncthreads();   // everyone done with previous K/V (and Q preload on it=0)
        stage_rows(Kg + ((size_t)bh * SEQ + it * 64) * DH, Ks, t, DH, 2);
        stage_rows(Vt + (size_t)bh * DH * SEQ + it * 64, Vts, t, SEQ, 2);
        __syncthreads();   // staging visible
        if (!masking)       attn_tile<2>(Ks, Vts, Pw, Qf, bias, oacc, lane, quad, l15, qloc);
        else if (it == qt)  attn_tile<1>(Ks, Vts, Pw, Qf, bias, oacc, lane, quad, l15, qloc);
        else                attn_tile<0>(Ks, Vts, Pw, Qf, bias, oacc, lane, quad, l15, qloc);
        #pragma unroll
        for (int mt = 0; mt < 4; ++mt)
            #pragma unroll
            for (int i = 0; i < 4; ++i)
                bias[mt][i] += 64.f * SCALE2;
    }

    // epilogue: D[e][q] -> attnb[b][q][h*64+e], 4 consecutive e packed (8 B)
    #pragma unroll
    for (int mt = 0; mt < 4; ++mt) {
        int e = mt * 16 + quad * 4;
        int q = q0 + wave * 16 + l15;
        short4v o;
        #pragma unroll
        for (int i = 0; i < 4; ++i) o[i] = f2bf(oacc[mt][i]);
        *(short4v*)(attnb + ((size_t)(b * SEQ + q)) * DMODEL + h * DH + e) = o;
    }
}

extern "C" void kernel_launch(void* const* d_in, const int* in_sizes, int n_in,
                              void* d_out, int out_size, void* d_ws, size_t ws_size,
                              hipStream_t stream) {
    const float* keys    = (const float*)d_in[0];
    const float* queries = (const float*)d_in[1];
    const float* values  = (const float*)d_in[2];
    const float* WQ      = (const float*)d_in[3];
    const float* WK      = (const float*)d_in[4];
    const float* WV      = (const float*)d_in[5];
    const float* WO      = (const float*)d_in[6];
    const int*   mask_p  = (const int*)d_in[7];
    float* out = (float*)d_out;

    const size_t nX = (size_t)NB * SEQ * DMODEL;   // 4,194,304
    const size_t nW = (size_t)DMODEL * DMODEL;     // 1,048,576
    const size_t nQ = (size_t)BHN * SEQ * DH;      // 4,194,304

    short* ws = (short*)d_ws;
    short* Xq    = ws;
    short* Xk    = Xq + nX;
    short* Xv    = Xk + nX;
    short* WQt   = Xv + nX;
    short* WKt   = WQt + nW;
    short* WVt   = WKt + nW;
    short* WOt   = WVt + nW;
    short* Qg    = WOt + nW;      // [bh][s][64] bf16
    short* Kg    = Qg + nQ;
    short* Vtg   = Kg + nQ;       // [bh][e][s] bf16 (pre-transposed V; scaled in stats)
    short* attnb = Vtg + nQ;      // [b][s][1024] bf16

    convert_x<<<dim3(2048, 1, 3), dim3(256), 0, stream>>>(queries, keys, values, Xq, Xk, Xv);
    convert_w<<<dim3(16, 16, 4), dim3(256), 0, stream>>>(WQ, WK, WV, WO, WQt, WKt, WVt, WOt);
    gemm_nt<<<dim3(8, 32, 3), dim3(256), 0, stream>>>(
        Xq, Xk, Xv, WQt, WKt, WVt, Qg, Kg, Vtg, nullptr, 0);
    stats_mfma<<<dim3(32, 32), dim3(256), 0, stream>>>(Qg, Kg, Vtg, mask_p);
    attn_mfma<<<dim3(32, 32), dim3(256), 0, stream>>>(Qg, Kg, Vtg, attnb, mask_p);
    // argument order: (A0,A1,A2, B0,B1,B2, Y0,Y1,Y2, outF, phase) — WOt in B0.
    gemm_nt<<<dim3(8, 32, 1), dim3(256), 0, stream>>>(
        attnb, nullptr, nullptr, WOt, nullptr, nullptr, nullptr, nullptr, nullptr, out, 1);
}